// Round 6
// baseline (226.134 us; speedup 1.0000x reference)
//
#include <hip/hip_runtime.h>

// Problem constants: x [32,112,112,128] fp32, W [7,7,2,1] HWIO, b [1]
static constexpr int Bn = 32;
static constexpr int Hn = 112;
static constexpr int Wn = 112;
static constexpr int HALO = 3;
static constexpr int NROWS = Bn * Hn;          // 3584 blocks, = 8 * 448

typedef float floatx4 __attribute__((ext_vector_type(4)));

// ---------------------------------------------------------------------------
// Single fused kernel. Block = one image row (b, r). 256 threads = 8 groups
// of 32 lanes (one group = one pixel's 128 channels as 32 float4).
//
//  Phase 0: load the CENTER row's x into registers (14 float4/thread),
//           issued first so HBM latency hides under phase A.
//  Phase A: channel stats (mean,max) for rows r-3..r+3 -> LDS, zero-padded.
//           Halo rows are read from global; 6 of 7 rows are re-reads that hit
//           the same-XCD L2 thanks to the chunked block swizzle.
//  Phase B: 7x7x2 conv + bias + sigmoid -> 112 gates in LDS.
//  Phase C: out = xv(reg) * gate, non-temporal store. x is never re-read.
//
// XCD swizzle: blockIdx round-robins across the 8 XCDs, so bid&7 is the XCD;
// giving each XCD a contiguous 448-row chunk makes halo re-reads L2-local.
// ---------------------------------------------------------------------------
__global__ __launch_bounds__(256) void fused_row_kernel(const float* __restrict__ x,
                                                        const float* __restrict__ Wc,
                                                        const float* __restrict__ bias,
                                                        float* __restrict__ out) {
    __shared__ float2 sdat[7][Wn + 2 * HALO];  // 7 x 118 float2 (6.6 KB), zero-padded
    __shared__ float  glds[Wn];
    __shared__ float  w[98];

    // XCD-chunked swizzle: NROWS = 8 * 448
    const int work = (blockIdx.x & 7) * (NROWS / 8) + (blockIdx.x >> 3);
    const int b = work / Hn;
    const int r = work % Hn;

    const int tid  = threadIdx.x;
    const int lane = tid & 31;
    const int grp  = tid >> 5;                 // 8 pixel-groups

    if (tid < 98) w[tid] = Wc[tid];
    for (int i = tid; i < 7 * (Wn + 2 * HALO); i += 256)
        ((float2*)sdat)[i] = make_float2(0.f, 0.f);
    __syncthreads();

    const floatx4* __restrict__ x4 = reinterpret_cast<const floatx4*>(x);
    const size_t imgbase = (size_t)b * Hn * Wn * 32;   // in float4 units

    // ---- phase 0: center row x -> registers (issued first) ----------------
    floatx4 xv[14];
#pragma unroll
    for (int j = 0; j < 14; ++j) {
        const int c = grp + 8 * j;
        xv[j] = x4[imgbase + ((size_t)r * Wn + c) * 32 + lane];
    }

    // ---- phase A1: center-row stats from registers ------------------------
#pragma unroll
    for (int j = 0; j < 14; ++j) {
        const int c = grp + 8 * j;
        const floatx4 v = xv[j];
        float s = v.x + v.y + v.z + v.w;
        float m = fmaxf(fmaxf(v.x, v.y), fmaxf(v.z, v.w));
#pragma unroll
        for (int off = 16; off >= 1; off >>= 1) {
            s += __shfl_xor(s, off);
            m = fmaxf(m, __shfl_xor(m, off));
        }
        if (lane == 0) sdat[HALO][c + HALO] = make_float2(s * (1.0f / 128.0f), m);
    }

    // ---- phase A2: halo-row stats (6 rows x 112 pixels, L2-hot) ------------
    for (int p = grp; p < 6 * Wn; p += 8) {
        const int kr0 = p / Wn;                // 0..5
        const int kr  = kr0 + (kr0 >= HALO);   // 0,1,2,4,5,6 (skip center)
        const int c   = p % Wn;
        const int rr  = r - HALO + kr;
        if (rr >= 0 && rr < Hn) {
            const floatx4 v = x4[imgbase + ((size_t)rr * Wn + c) * 32 + lane];
            float s = v.x + v.y + v.z + v.w;
            float m = fmaxf(fmaxf(v.x, v.y), fmaxf(v.z, v.w));
#pragma unroll
            for (int off = 16; off >= 1; off >>= 1) {
                s += __shfl_xor(s, off);
                m = fmaxf(m, __shfl_xor(m, off));
            }
            if (lane == 0) sdat[kr][c + HALO] = make_float2(s * (1.0f / 128.0f), m);
        }
        // out-of-image rows stay zero (exact for SAME zero padding)
    }
    __syncthreads();

    // ---- phase B: 7x7 conv + bias + sigmoid -> gate ------------------------
    if (tid < Wn) {
        float acc = bias[0];
#pragma unroll
        for (int kh = 0; kh < 7; ++kh)
#pragma unroll
            for (int kw = 0; kw < 7; ++kw) {
                const float2 sv = sdat[kh][tid + kw];
                acc = fmaf(sv.x, w[(kh * 7 + kw) * 2 + 0], acc);
                acc = fmaf(sv.y, w[(kh * 7 + kw) * 2 + 1], acc);
            }
        glds[tid] = 1.0f / (1.0f + expf(-acc));
    }
    __syncthreads();

    // ---- phase C: out = xv * gate, NT store --------------------------------
    floatx4* __restrict__ o4 = reinterpret_cast<floatx4*>(out);
#pragma unroll
    for (int j = 0; j < 14; ++j) {
        const int c = grp + 8 * j;
        floatx4 v = xv[j];
        v *= glds[c];                          // broadcast within group
        __builtin_nontemporal_store(v, &o4[imgbase + ((size_t)r * Wn + c) * 32 + lane]);
    }
}

extern "C" void kernel_launch(void* const* d_in, const int* in_sizes, int n_in,
                              void* d_out, int out_size, void* d_ws, size_t ws_size,
                              hipStream_t stream) {
    const float* x  = (const float*)d_in[0];
    const float* Wc = (const float*)d_in[1];
    const float* bb = (const float*)d_in[2];
    float* out = (float*)d_out;

    fused_row_kernel<<<NROWS, 256, 0, stream>>>(x, Wc, bb, out);
}

// Round 7
// 199.511 us; speedup vs baseline: 1.1334x; 1.1334x over previous
//
#include <hip/hip_runtime.h>

// Problem constants: x [32,112,112,128] fp32, W [7,7,2,1] HWIO, b [1]
static constexpr int Bn = 32;
static constexpr int Hn = 112;
static constexpr int Wn = 112;
static constexpr int HALO = 3;
static constexpr int NROWS = Bn * Hn;          // 3584 blocks, block = one image row
static constexpr int SPIN_MAX = 200;           // ~few µs, then fallback recompute

typedef float floatx4 __attribute__((ext_vector_type(4)));

// ---------------------------------------------------------------------------
// Producer-consumer fused kernel. Block = image row (b, r), bid == row id so
// dependencies span only +-3 block ids (dispatch is monotone in practice;
// correctness does NOT depend on it thanks to the recompute fallback).
//
//  P1: stats (mean,max over 128ch) of OWN row -> LDS + global, release flag.
//  P2: lanes 0..6 spin on neighbor-row flags (bounded); rows that time out
//      are recomputed from x (same values -> correct under any schedule).
//  P3: 7x7x2 conv + bias + sigmoid -> gate in LDS.
//  P4: re-read own row's x (L2/L3-hot: fetched ~2us ago, NT out-stores don't
//      displace it), multiply, non-temporal store.
// x is fetched from HBM exactly once; halo traffic is stats (896 B/row).
// ---------------------------------------------------------------------------
__global__ __launch_bounds__(256) void fused_pc_kernel(const float* __restrict__ x,
                                                       const float* __restrict__ Wc,
                                                       const float* __restrict__ bias,
                                                       float2* __restrict__ stats,
                                                       int* __restrict__ flags,
                                                       float* __restrict__ out) {
    __shared__ float2 sdat[7][Wn + 2 * HALO];  // zero-padded stat tile (6.6 KB)
    __shared__ float  glds[Wn];
    __shared__ float  w[98];
    __shared__ int    rowstate[7];             // 0=own,1=load from global,2=zero,3=recompute

    const int wid  = blockIdx.x;               // == b*Hn + r
    const int b    = wid / Hn;
    const int r    = wid % Hn;
    const int tid  = threadIdx.x;
    const int lane = tid & 31;
    const int grp  = tid >> 5;                 // 8 groups; group = one pixel's 32 float4

    if (tid < 98) w[tid] = Wc[tid];
    for (int i = tid; i < 7 * (Wn + 2 * HALO); i += 256)
        ((float2*)sdat)[i] = make_float2(0.f, 0.f);
    __syncthreads();

    const floatx4* __restrict__ x4 = reinterpret_cast<const floatx4*>(x);
    const size_t imgbase = (size_t)b * Hn * Wn * 32;     // float4 units
    const size_t rowbase = imgbase + (size_t)r * Wn * 32;

    // ---- P1: own-row stats -> sdat[3][*] and global; publish flag ---------
#pragma unroll
    for (int j = 0; j < 14; ++j) {
        const int c = grp + 8 * j;
        const floatx4 v = x4[rowbase + (size_t)c * 32 + lane];
        float s = v.x + v.y + v.z + v.w;
        float m = fmaxf(fmaxf(v.x, v.y), fmaxf(v.z, v.w));
#pragma unroll
        for (int off = 16; off >= 1; off >>= 1) {
            s += __shfl_xor(s, off);
            m = fmaxf(m, __shfl_xor(m, off));
        }
        if (lane == 0) {
            const float2 sm = make_float2(s * (1.0f / 128.0f), m);
            sdat[HALO][c + HALO] = sm;
            stats[(size_t)wid * Wn + c] = sm;
        }
    }
    __syncthreads();   // all stats stores issued before the release below
    if (tid == 0)
        __hip_atomic_store(&flags[wid], 1, __ATOMIC_RELEASE, __HIP_MEMORY_SCOPE_AGENT);

    // ---- P2a: lane-parallel bounded spin on 6 neighbor flags ---------------
    if (tid < 7) {
        int st = 0;                                      // own row
        if (tid != HALO) {
            const int rr = r - HALO + tid;
            if (rr < 0 || rr >= Hn) st = 2;              // zero padding row
            else {
                const int f = wid - HALO + tid;
                int it = 0;
                while (__hip_atomic_load(&flags[f], __ATOMIC_RELAXED,
                                         __HIP_MEMORY_SCOPE_AGENT) == 0 &&
                       ++it < SPIN_MAX) {}
                st = (__hip_atomic_load(&flags[f], __ATOMIC_ACQUIRE,
                                        __HIP_MEMORY_SCOPE_AGENT) != 0) ? 1 : 3;
            }
        }
        rowstate[tid] = st;
    }
    __syncthreads();

    // ---- P2b: bulk-load published halo stats rows ---------------------------
    for (int p = tid; p < 7 * Wn; p += 256) {
        const int kr = p / Wn;
        const int c  = p % Wn;
        if (rowstate[kr] == 1)
            sdat[kr][c + HALO] = stats[(size_t)(wid - HALO + kr) * Wn + c];
    }
    // ---- P2c: fallback recompute for unpublished rows (rare) ---------------
    for (int kr = 0; kr < 7; ++kr) {
        if (rowstate[kr] != 3) continue;                 // uniform across block
        const int rr = r - HALO + kr;
        for (int pc = grp; pc < Wn; pc += 8) {
            const floatx4 v = x4[imgbase + ((size_t)rr * Wn + pc) * 32 + lane];
            float s = v.x + v.y + v.z + v.w;
            float m = fmaxf(fmaxf(v.x, v.y), fmaxf(v.z, v.w));
#pragma unroll
            for (int off = 16; off >= 1; off >>= 1) {
                s += __shfl_xor(s, off);
                m = fmaxf(m, __shfl_xor(m, off));
            }
            if (lane == 0) sdat[kr][pc + HALO] = make_float2(s * (1.0f / 128.0f), m);
        }
    }
    __syncthreads();

    // ---- P3: 7x7 conv + bias + sigmoid -> gate ------------------------------
    if (tid < Wn) {
        float acc = bias[0];
#pragma unroll
        for (int kh = 0; kh < 7; ++kh)
#pragma unroll
            for (int kw = 0; kw < 7; ++kw) {
                const float2 sv = sdat[kh][tid + kw];
                acc = fmaf(sv.x, w[(kh * 7 + kw) * 2 + 0], acc);
                acc = fmaf(sv.y, w[(kh * 7 + kw) * 2 + 1], acc);
            }
        glds[tid] = 1.0f / (1.0f + expf(-acc));
    }
    __syncthreads();

    // ---- P4: out = x * gate (x re-read is L2/L3-hot), NT store -------------
    floatx4* __restrict__ o4 = reinterpret_cast<floatx4*>(out);
#pragma unroll
    for (int j = 0; j < 14; ++j) {
        const int c = grp + 8 * j;
        floatx4 v = x4[rowbase + (size_t)c * 32 + lane];
        v *= glds[c];
        __builtin_nontemporal_store(v, &o4[rowbase + (size_t)c * 32 + lane]);
    }
}

extern "C" void kernel_launch(void* const* d_in, const int* in_sizes, int n_in,
                              void* d_out, int out_size, void* d_ws, size_t ws_size,
                              hipStream_t stream) {
    const float* x  = (const float*)d_in[0];
    const float* Wc = (const float*)d_in[1];
    const float* bb = (const float*)d_in[2];
    float* out = (float*)d_out;

    // workspace: stats float2[NROWS*Wn] (3.2 MB) then flags int[NROWS] (14 KB)
    float2* stats = (float2*)d_ws;
    int*    flags = (int*)((char*)d_ws + (size_t)NROWS * Wn * sizeof(float2));

    hipMemsetAsync(flags, 0, NROWS * sizeof(int), stream);
    fused_pc_kernel<<<NROWS, 256, 0, stream>>>(x, Wc, bb, stats, flags, out);
}

// Round 8
// 112.847 us; speedup vs baseline: 2.0039x; 1.7680x over previous
//
#include <hip/hip_runtime.h>

// Problem constants: x [32,112,112,128] fp32, W [7,7,2,1] HWIO, b [1]
static constexpr int Bn = 32;
static constexpr int Hn = 112;
static constexpr int Wn = 112;
static constexpr int HALO = 3;
static constexpr int NROWS = Bn * Hn;          // 3584 blocks, block = one image row
static constexpr int SPIN_MAX = 150;           // bounded; fallback recompute after

typedef float floatx4 __attribute__((ext_vector_type(4)));

union f2u { float2 f; unsigned long long u; };

// ---------------------------------------------------------------------------
// Fence-free producer-consumer fused kernel. Block = image row (b, r).
//
//  P1: stats (mean,max over 128ch) of OWN row -> LDS; publish to global via
//      RELAXED agent-scope atomic u64 stores (sc0 sc1 -> straight to MALL,
//      no L2 writeback/invalidate). s_waitcnt vmcnt(0) + barrier, then flag.
//  P2: lanes 0..6 spin on neighbor flags with RELAXED atomic loads (bypass
//      L1/L2 -> always-fresh MALL reads, no invalidation side effects).
//      Timeout -> recompute that row from x (identical values => correct
//      under any dispatch schedule).
//  P3: 7x7x2 conv + bias + sigmoid -> gate in LDS.
//  P4: re-read own row's x with PLAIN cached loads (L2/MALL hot, x is
//      read-only so no staleness), multiply, non-temporal store.
//
// x is fetched from HBM exactly once; halo traffic is 8B-stats, KB-scale.
// The R7 failure (256us) was acquire/release fences nuking per-XCD L2;
// this version contains ZERO cache-maintenance operations.
// ---------------------------------------------------------------------------
__global__ __launch_bounds__(256) void fused_pc2_kernel(const float* __restrict__ x,
                                                        const float* __restrict__ Wc,
                                                        const float* __restrict__ bias,
                                                        unsigned long long* __restrict__ stats,
                                                        int* __restrict__ flags,
                                                        float* __restrict__ out) {
    __shared__ float2 sdat[7][Wn + 2 * HALO];  // zero-padded stat tile (6.6 KB)
    __shared__ float  glds[Wn];
    __shared__ float  w[98];
    __shared__ int    rowstate[7];             // 0=own,1=from global,2=zero,3=recompute

    const int wid  = blockIdx.x;               // == b*Hn + r
    const int b    = wid / Hn;
    const int r    = wid % Hn;
    const int tid  = threadIdx.x;
    const int lane = tid & 31;
    const int grp  = tid >> 5;                 // 8 groups; group = one pixel (32 float4)

    if (tid < 98) w[tid] = Wc[tid];
    for (int i = tid; i < 7 * (Wn + 2 * HALO); i += 256)
        ((float2*)sdat)[i] = make_float2(0.f, 0.f);
    __syncthreads();

    const floatx4* __restrict__ x4 = reinterpret_cast<const floatx4*>(x);
    const size_t rowbase = (size_t)wid * Wn * 32;        // float4 units

    // ---- P1: own-row stats -> LDS + global (relaxed sc1 stores) -----------
#pragma unroll
    for (int j = 0; j < 14; ++j) {
        const int c = grp + 8 * j;
        const floatx4 v = x4[rowbase + (size_t)c * 32 + lane];
        float s = v.x + v.y + v.z + v.w;
        float m = fmaxf(fmaxf(v.x, v.y), fmaxf(v.z, v.w));
#pragma unroll
        for (int off = 16; off >= 1; off >>= 1) {
            s += __shfl_xor(s, off);
            m = fmaxf(m, __shfl_xor(m, off));
        }
        if (lane == 0) {
            f2u t; t.f = make_float2(s * (1.0f / 128.0f), m);
            sdat[HALO][c + HALO] = t.f;
            __hip_atomic_store(&stats[(size_t)wid * Wn + c], t.u,
                               __ATOMIC_RELAXED, __HIP_MEMORY_SCOPE_AGENT);
        }
    }
    asm volatile("s_waitcnt vmcnt(0)" ::: "memory");     // stats stores complete
    __syncthreads();                                     // ... across all waves
    if (tid == 0)
        __hip_atomic_store(&flags[wid], 1, __ATOMIC_RELAXED, __HIP_MEMORY_SCOPE_AGENT);

    // ---- P2a: lane-parallel bounded spin (relaxed loads, no fences) --------
    if (tid < 7) {
        int st = 0;                                      // own row
        if (tid != HALO) {
            const int rr = r - HALO + tid;
            if (rr < 0 || rr >= Hn) st = 2;              // zero-padding row
            else {
                const int f = wid - HALO + tid;
                int it = 0, got = 0;
                do {
                    got = __hip_atomic_load(&flags[f], __ATOMIC_RELAXED,
                                            __HIP_MEMORY_SCOPE_AGENT);
                } while (!got && ++it < SPIN_MAX);
                st = got ? 1 : 3;
            }
        }
        rowstate[tid] = st;
    }
    __syncthreads();

    // ---- P2b: bulk-load published halo stats (relaxed u64 loads from MALL) -
    for (int p = tid; p < 7 * Wn; p += 256) {
        const int kr = p / Wn;
        const int c  = p % Wn;
        if (rowstate[kr] == 1) {
            f2u t;
            t.u = __hip_atomic_load(&stats[(size_t)(wid - HALO + kr) * Wn + c],
                                    __ATOMIC_RELAXED, __HIP_MEMORY_SCOPE_AGENT);
            sdat[kr][c + HALO] = t.f;
        }
    }
    // ---- P2c: fallback recompute for unpublished rows (rare, correct) ------
    for (int kr = 0; kr < 7; ++kr) {
        if (rowstate[kr] != 3) continue;                 // uniform across block
        const int rr = r - HALO + kr;
        const size_t rb = ((size_t)(b * Hn + rr)) * Wn * 32;
        for (int pc = grp; pc < Wn; pc += 8) {
            const floatx4 v = x4[rb + (size_t)pc * 32 + lane];
            float s = v.x + v.y + v.z + v.w;
            float m = fmaxf(fmaxf(v.x, v.y), fmaxf(v.z, v.w));
#pragma unroll
            for (int off = 16; off >= 1; off >>= 1) {
                s += __shfl_xor(s, off);
                m = fmaxf(m, __shfl_xor(m, off));
            }
            if (lane == 0) sdat[kr][pc + HALO] = make_float2(s * (1.0f / 128.0f), m);
        }
    }
    __syncthreads();

    // ---- P3: 7x7 conv + bias + sigmoid -> gate ------------------------------
    if (tid < Wn) {
        float acc = bias[0];
#pragma unroll
        for (int kh = 0; kh < 7; ++kh)
#pragma unroll
            for (int kw = 0; kw < 7; ++kw) {
                const float2 sv = sdat[kh][tid + kw];
                acc = fmaf(sv.x, w[(kh * 7 + kw) * 2 + 0], acc);
                acc = fmaf(sv.y, w[(kh * 7 + kw) * 2 + 1], acc);
            }
        glds[tid] = 1.0f / (1.0f + expf(-acc));
    }
    __syncthreads();

    // ---- P4: out = x * gate (cached re-read: L2/MALL-hot), NT store --------
    floatx4* __restrict__ o4 = reinterpret_cast<floatx4*>(out);
#pragma unroll
    for (int j = 0; j < 14; ++j) {
        const int c = grp + 8 * j;
        floatx4 v = x4[rowbase + (size_t)c * 32 + lane];
        v *= glds[c];
        __builtin_nontemporal_store(v, &o4[rowbase + (size_t)c * 32 + lane]);
    }
}

extern "C" void kernel_launch(void* const* d_in, const int* in_sizes, int n_in,
                              void* d_out, int out_size, void* d_ws, size_t ws_size,
                              hipStream_t stream) {
    const float* x  = (const float*)d_in[0];
    const float* Wc = (const float*)d_in[1];
    const float* bb = (const float*)d_in[2];
    float* out = (float*)d_out;

    // workspace: stats u64[NROWS*Wn] (3.2 MB) then flags int[NROWS] (14 KB)
    unsigned long long* stats = (unsigned long long*)d_ws;
    int* flags = (int*)((char*)d_ws + (size_t)NROWS * Wn * sizeof(unsigned long long));

    hipMemsetAsync(flags, 0, NROWS * sizeof(int), stream);
    fused_pc2_kernel<<<NROWS, 256, 0, stream>>>(x, Wc, bb, stats, flags, out);
}

// Round 9
// 88.303 us; speedup vs baseline: 2.5609x; 1.2780x over previous
//
#include <hip/hip_runtime.h>

// Problem constants: x [32,112,112,128] fp32, W [7,7,2,1] HWIO, b [1]
static constexpr int Bn = 32;
static constexpr int Hn = 112;
static constexpr int Wn = 112;
static constexpr int HALO = 3;
static constexpr int NROWS = Bn * Hn;          // 3584 blocks, block = one image row
static constexpr int SPIN_MAX = 150;           // bounded; fallback recompute after

typedef float floatx4 __attribute__((ext_vector_type(4)));

union f2u { float2 f; unsigned long long u; };

// ---------------------------------------------------------------------------
// Register-resident producer-consumer fused kernel. Block = image row (b, r).
//
//  P0: load the row's x into registers (14 float4/thread) at kernel entry.
//  P1: stats (mean,max over 128ch) from registers -> LDS + global via RELAXED
//      agent-scope u64 stores (straight to MALL, no cache maintenance);
//      s_waitcnt vmcnt(0) + barrier; publish flag (relaxed).
//      Then PIN the 56 x-floats with empty asm so the compiler must keep
//      them live to P4 (R6 showed it otherwise reloads x -> +205 MB MALL).
//  P2: bounded spin on neighbor flags (relaxed loads); timeout -> recompute
//      that row from x (identical values => correct under any schedule).
//  P3: 7x7x2 conv + bias + sigmoid -> gate in LDS.
//  P4: out = x(reg) * gate, non-temporal store. x is never re-read.
//
// HBM traffic: x once (205 MB) + out once (205 MB) + KB-scale stats. The
// R8 lesson: MALL hits have no BW advantage, so the only way below ~88us
// is to not touch x a second time at all.
// ---------------------------------------------------------------------------
__global__ __launch_bounds__(256) void fused_reg_kernel(const float* __restrict__ x,
                                                        const float* __restrict__ Wc,
                                                        const float* __restrict__ bias,
                                                        unsigned long long* __restrict__ stats,
                                                        int* __restrict__ flags,
                                                        float* __restrict__ out) {
    __shared__ float2 sdat[7][Wn + 2 * HALO];  // zero-padded stat tile (6.6 KB)
    __shared__ float  glds[Wn];
    __shared__ float  w[98];
    __shared__ int    rowstate[7];             // 0=own,1=from global,2=zero,3=recompute

    const int wid  = blockIdx.x;               // == b*Hn + r
    const int b    = wid / Hn;
    const int r    = wid % Hn;
    const int tid  = threadIdx.x;
    const int lane = tid & 31;
    const int grp  = tid >> 5;                 // 8 groups; group = one pixel (32 float4)

    const floatx4* __restrict__ x4 = reinterpret_cast<const floatx4*>(x);
    const size_t rowbase = (size_t)wid * Wn * 32;        // float4 units

    // ---- P0: own-row x -> registers (issued first, hides HBM latency) -----
    float xa[14], xb[14], xc[14], xd[14];
#pragma unroll
    for (int j = 0; j < 14; ++j) {
        const int c = grp + 8 * j;
        const floatx4 v = x4[rowbase + (size_t)c * 32 + lane];
        xa[j] = v.x; xb[j] = v.y; xc[j] = v.z; xd[j] = v.w;
    }

    if (tid < 98) w[tid] = Wc[tid];
    for (int i = tid; i < 7 * (Wn + 2 * HALO); i += 256)
        ((float2*)sdat)[i] = make_float2(0.f, 0.f);
    __syncthreads();

    // ---- P1: own-row stats from registers -> LDS + global (relaxed) -------
#pragma unroll
    for (int j = 0; j < 14; ++j) {
        const int c = grp + 8 * j;
        float s = xa[j] + xb[j] + xc[j] + xd[j];
        float m = fmaxf(fmaxf(xa[j], xb[j]), fmaxf(xc[j], xd[j]));
#pragma unroll
        for (int off = 16; off >= 1; off >>= 1) {
            s += __shfl_xor(s, off);
            m = fmaxf(m, __shfl_xor(m, off));
        }
        if (lane == 0) {
            f2u t; t.f = make_float2(s * (1.0f / 128.0f), m);
            sdat[HALO][c + HALO] = t.f;
            __hip_atomic_store(&stats[(size_t)wid * Wn + c], t.u,
                               __ATOMIC_RELAXED, __HIP_MEMORY_SCOPE_AGENT);
        }
    }

    // Pin the row's x in registers: empty asm "modifies" them, so the
    // compiler cannot rematerialize from memory and must keep them live.
#pragma unroll
    for (int j = 0; j < 14; ++j)
        asm volatile("" : "+v"(xa[j]), "+v"(xb[j]), "+v"(xc[j]), "+v"(xd[j]));

    asm volatile("s_waitcnt vmcnt(0)" ::: "memory");     // stats stores complete
    __syncthreads();
    if (tid == 0)
        __hip_atomic_store(&flags[wid], 1, __ATOMIC_RELAXED, __HIP_MEMORY_SCOPE_AGENT);

    // ---- P2a: lane-parallel bounded spin (relaxed loads, no fences) --------
    if (tid < 7) {
        int st = 0;                                      // own row
        if (tid != HALO) {
            const int rr = r - HALO + tid;
            if (rr < 0 || rr >= Hn) st = 2;              // zero-padding row
            else {
                const int f = wid - HALO + tid;
                int it = 0, got = 0;
                do {
                    got = __hip_atomic_load(&flags[f], __ATOMIC_RELAXED,
                                            __HIP_MEMORY_SCOPE_AGENT);
                } while (!got && ++it < SPIN_MAX);
                st = got ? 1 : 3;
            }
        }
        rowstate[tid] = st;
    }
    __syncthreads();

    // ---- P2b: bulk-load published halo stats (relaxed u64 from MALL) -------
    for (int p = tid; p < 7 * Wn; p += 256) {
        const int kr = p / Wn;
        const int c  = p % Wn;
        if (rowstate[kr] == 1) {
            f2u t;
            t.u = __hip_atomic_load(&stats[(size_t)(wid - HALO + kr) * Wn + c],
                                    __ATOMIC_RELAXED, __HIP_MEMORY_SCOPE_AGENT);
            sdat[kr][c + HALO] = t.f;
        }
    }
    // ---- P2c: fallback recompute for unpublished rows (rare, correct) ------
    for (int kr = 0; kr < 7; ++kr) {
        if (rowstate[kr] != 3) continue;                 // uniform across block
        const int rr = r - HALO + kr;
        const size_t rb = ((size_t)(b * Hn + rr)) * Wn * 32;
        for (int pc = grp; pc < Wn; pc += 8) {
            const floatx4 v = x4[rb + (size_t)pc * 32 + lane];
            float s = v.x + v.y + v.z + v.w;
            float m = fmaxf(fmaxf(v.x, v.y), fmaxf(v.z, v.w));
#pragma unroll
            for (int off = 16; off >= 1; off >>= 1) {
                s += __shfl_xor(s, off);
                m = fmaxf(m, __shfl_xor(m, off));
            }
            if (lane == 0) sdat[kr][pc + HALO] = make_float2(s * (1.0f / 128.0f), m);
        }
    }
    __syncthreads();

    // ---- P3: 7x7 conv + bias + sigmoid -> gate ------------------------------
    if (tid < Wn) {
        float acc = bias[0];
#pragma unroll
        for (int kh = 0; kh < 7; ++kh)
#pragma unroll
            for (int kw = 0; kw < 7; ++kw) {
                const float2 sv = sdat[kh][tid + kw];
                acc = fmaf(sv.x, w[(kh * 7 + kw) * 2 + 0], acc);
                acc = fmaf(sv.y, w[(kh * 7 + kw) * 2 + 1], acc);
            }
        glds[tid] = 1.0f / (1.0f + expf(-acc));
    }
    __syncthreads();

    // ---- P4: out = x(reg) * gate, NT store (x never re-read) ---------------
    floatx4* __restrict__ o4 = reinterpret_cast<floatx4*>(out);
#pragma unroll
    for (int j = 0; j < 14; ++j) {
        const int c = grp + 8 * j;
        const float g = glds[c];
        floatx4 v;
        v.x = xa[j] * g; v.y = xb[j] * g; v.z = xc[j] * g; v.w = xd[j] * g;
        __builtin_nontemporal_store(v, &o4[rowbase + (size_t)c * 32 + lane]);
    }
}

extern "C" void kernel_launch(void* const* d_in, const int* in_sizes, int n_in,
                              void* d_out, int out_size, void* d_ws, size_t ws_size,
                              hipStream_t stream) {
    const float* x  = (const float*)d_in[0];
    const float* Wc = (const float*)d_in[1];
    const float* bb = (const float*)d_in[2];
    float* out = (float*)d_out;

    // workspace: stats u64[NROWS*Wn] (3.2 MB) then flags int[NROWS] (14 KB)
    unsigned long long* stats = (unsigned long long*)d_ws;
    int* flags = (int*)((char*)d_ws + (size_t)NROWS * Wn * sizeof(unsigned long long));

    hipMemsetAsync(flags, 0, NROWS * sizeof(int), stream);
    fused_reg_kernel<<<NROWS, 256, 0, stream>>>(x, Wc, bb, stats, flags, out);
}